// Round 1
// baseline (2133.344 us; speedup 1.0000x reference)
//
#include <hip/hip_runtime.h>
#include <hip/hip_bf16.h>

typedef __hip_bfloat16 bf16;

// Geometry: B=16, C=128, H=W=128, HW=16384, S1=S2=64
// h buffer (bf16) layout: (B, 256, HW); ch 0..63 = a1, 64..127 = a2, 128..255 = xh

// ---------------------------------------------------------------------------
// K1: fused LayerNorm (over C) + pointwise 128->256 GEMM, output bf16.
// One block = 64 consecutive pixels (same batch image), 256 threads.
// ---------------------------------------------------------------------------
__global__ __launch_bounds__(256) void ln_pf_kernel(
    const float* __restrict__ x, const float* __restrict__ ln_w,
    const float* __restrict__ ln_b, const float* __restrict__ pf_w,
    const float* __restrict__ pf_b, bf16* __restrict__ h)
{
  __shared__ float xs[128 * 64];
  __shared__ float meanv[64];
  __shared__ float rstdv[64];
  const int tid = threadIdx.x;
  const int g0 = blockIdx.x * 64;       // global pixel base (b*HW + hw)
  const int b = g0 >> 14;
  const int hw0 = g0 & 16383;
  const float* xb = x + (long)b * (128L * 16384) + hw0;

  #pragma unroll
  for (int i = 0; i < 32; ++i) {        // 8192 elems / 256 threads
    int idx = i * 256 + tid;
    int c = idx >> 6, p = idx & 63;
    xs[idx] = xb[(long)c * 16384 + p];
  }
  __syncthreads();

  if (tid < 64) {
    float s = 0.f, ss = 0.f;
    #pragma unroll 8
    for (int c = 0; c < 128; ++c) {
      float v = xs[c * 64 + tid];
      s += v; ss += v * v;
    }
    float m = s * 0.0078125f;
    float var = ss * 0.0078125f - m * m;
    meanv[tid] = m;
    rstdv[tid] = rsqrtf(var + 1e-6f);
  }
  __syncthreads();

  for (int i = 0; i < 32; ++i) {
    int idx = i * 256 + tid;
    int c = idx >> 6, p = idx & 63;
    float v = (xs[idx] - meanv[p]) * rstdv[p];
    xs[idx] = v * ln_w[c] + ln_b[c];
  }
  __syncthreads();

  const int p = tid & 63;
  const int wv = __builtin_amdgcn_readfirstlane(tid >> 6);  // wave id 0..3
  const int ocBase = wv * 64;                               // 64 ocs per wave
  bf16* hp = h + ((long)b * 256) * 16384 + hw0 + p;

  for (int ocb = 0; ocb < 64; ocb += 16) {
    float acc[16];
    const float* wbase = pf_w + (long)(ocBase + ocb) * 128;
    #pragma unroll
    for (int j = 0; j < 16; ++j) acc[j] = pf_b[ocBase + ocb + j];
    #pragma unroll 4
    for (int ic = 0; ic < 128; ++ic) {
      float xv = xs[ic * 64 + p];
      #pragma unroll
      for (int j = 0; j < 16; ++j) acc[j] += wbase[j * 128 + ic] * xv;
    }
    #pragma unroll
    for (int j = 0; j < 16; ++j)
      hp[(long)(ocBase + ocb + j) * 16384] = __float2bfloat16(acc[j]);
  }
}

// ---------------------------------------------------------------------------
// Generic depthwise conv (64 channels), cross-correlation, zero pad, bf16 io.
// Thread per output element; channel is wave-uniform -> scalar weights.
// ---------------------------------------------------------------------------
template <int KH, int KW, int DIL, int PADH, int PADW>
__global__ __launch_bounds__(256) void dwconv_kernel(
    const bf16* __restrict__ in, long inImgStride,
    const float* __restrict__ wt, const float* __restrict__ bias,
    bf16* __restrict__ out, long outImgStride)
{
  int id = blockIdx.x * 256 + threadIdx.x;  // over 16*64*16384 = 16,777,216
  int hw = id & 16383;
  int c = (id >> 14) & 63;
  int b = id >> 20;
  int cu = __builtin_amdgcn_readfirstlane(c);
  int yy = hw >> 7, xx = hw & 127;
  const bf16* ip = in + (long)b * inImgStride + (long)cu * 16384;
  float acc = bias[cu];
  #pragma unroll
  for (int u = 0; u < KH; ++u) {
    int y = yy - PADH + u * DIL;
    if ((unsigned)y < 128u) {
      #pragma unroll
      for (int v = 0; v < KW; ++v) {
        int xq = xx - PADW + v * DIL;
        if ((unsigned)xq < 128u)
          acc += wt[cu * (KH * KW) + u * KW + v] *
                 __bfloat162float(ip[y * 128 + xq]);
      }
    }
  }
  out[(long)b * outImgStride + (long)cu * 16384 + hw] = __float2bfloat16(acc);
}

// ---------------------------------------------------------------------------
// K4: fused finale. Per 64-pixel tile:
//   attn1 = (W4 @ d3 + b4) * x3o ; attn2 = (W5 @ d5 + b5) * x5o
//   g = xh * concat(attn1, attn2)
//   out = (PL @ g + pl_b) * scale + x
// ---------------------------------------------------------------------------
__global__ __launch_bounds__(256) void final_kernel(
    const bf16* __restrict__ h, const bf16* __restrict__ d3,
    const bf16* __restrict__ x3o, const bf16* __restrict__ d5,
    const bf16* __restrict__ x5o, const float* __restrict__ w4,
    const float* __restrict__ b4, const float* __restrict__ w5,
    const float* __restrict__ b5, const float* __restrict__ plw,
    const float* __restrict__ plb, const float* __restrict__ scale,
    const float* __restrict__ x, float* __restrict__ out)
{
  __shared__ float sm[128 * 64];  // phase 1: d3 rows 0..63, d5 rows 64..127; phase 2: g
  const int tid = threadIdx.x;
  const int p = tid & 63;
  const int wv = __builtin_amdgcn_readfirstlane(tid >> 6);
  const int g0 = blockIdx.x * 64;
  const int b = g0 >> 14;
  const int hw0 = g0 & 16383;
  const long base64 = (long)b * (64L * 16384) + hw0;

  #pragma unroll
  for (int i = 0; i < 16; ++i) {       // 4096/256
    int idx = i * 256 + tid;
    int c = idx >> 6, q = idx & 63;
    sm[idx]        = __bfloat162float(d3[base64 + (long)c * 16384 + q]);
    sm[4096 + idx] = __bfloat162float(d5[base64 + (long)c * 16384 + q]);
  }
  __syncthreads();

  float gv[32];
  #pragma unroll
  for (int j = 0; j < 16; ++j) {
    int oc = wv * 16 + j;
    float acc1 = b4[oc], acc2 = b5[oc];
    #pragma unroll 4
    for (int ic = 0; ic < 64; ++ic) {
      acc1 += w4[oc * 64 + ic] * sm[ic * 64 + p];
      acc2 += w5[oc * 64 + ic] * sm[4096 + ic * 64 + p];
    }
    float attn1 = acc1 * __bfloat162float(x3o[base64 + (long)oc * 16384 + p]);
    float attn2 = acc2 * __bfloat162float(x5o[base64 + (long)oc * 16384 + p]);
    float xh1 = __bfloat162float(h[((long)b * 256 + 128 + oc) * 16384 + hw0 + p]);
    float xh2 = __bfloat162float(h[((long)b * 256 + 192 + oc) * 16384 + hw0 + p]);
    gv[j]      = xh1 * attn1;
    gv[16 + j] = xh2 * attn2;
  }
  __syncthreads();
  #pragma unroll
  for (int j = 0; j < 16; ++j) {
    sm[(wv * 16 + j) * 64 + p]       = gv[j];
    sm[(64 + wv * 16 + j) * 64 + p]  = gv[16 + j];
  }
  __syncthreads();

  const int ocB = wv * 32;
  for (int ocb = 0; ocb < 32; ocb += 16) {
    float acc[16];
    const float* wbase = plw + (long)(ocB + ocb) * 128;
    #pragma unroll
    for (int j = 0; j < 16; ++j) acc[j] = plb[ocB + ocb + j];
    #pragma unroll 4
    for (int ic = 0; ic < 128; ++ic) {
      float gvv = sm[ic * 64 + p];
      #pragma unroll
      for (int j = 0; j < 16; ++j) acc[j] += wbase[j * 128 + ic] * gvv;
    }
    #pragma unroll
    for (int j = 0; j < 16; ++j) {
      int oc = ocB + ocb + j;
      long xi = ((long)b * 128 + oc) * 16384 + hw0 + p;
      out[xi] = acc[j] * scale[oc] + x[xi];
    }
  }
}

// ---------------------------------------------------------------------------
extern "C" void kernel_launch(void* const* d_in, const int* in_sizes, int n_in,
                              void* d_out, int out_size, void* d_ws, size_t ws_size,
                              hipStream_t stream)
{
  (void)in_sizes; (void)n_in; (void)out_size; (void)ws_size;
  const float* x       = (const float*)d_in[0];
  const float* ln_w    = (const float*)d_in[1];
  const float* ln_b    = (const float*)d_in[2];
  const float* scale   = (const float*)d_in[3];
  const float* pf_w    = (const float*)d_in[4];
  const float* pf_b    = (const float*)d_in[5];
  const float* lka3_w1 = (const float*)d_in[6];
  const float* lka3_b1 = (const float*)d_in[7];
  const float* lka3_w2 = (const float*)d_in[8];
  const float* lka3_b2 = (const float*)d_in[9];
  const float* lka3_w3 = (const float*)d_in[10];
  const float* lka3_b3 = (const float*)d_in[11];
  const float* lka3_w4 = (const float*)d_in[12];
  const float* lka3_b4 = (const float*)d_in[13];
  const float* lka5_w1 = (const float*)d_in[14];
  const float* lka5_b1 = (const float*)d_in[15];
  const float* lka5_w2 = (const float*)d_in[16];
  const float* lka5_b2 = (const float*)d_in[17];
  const float* lka5_w3 = (const float*)d_in[18];
  const float* lka5_b3 = (const float*)d_in[19];
  const float* x3a_w   = (const float*)d_in[20];
  const float* x3a_b   = (const float*)d_in[21];
  const float* x3b_w   = (const float*)d_in[22];
  const float* x3b_b   = (const float*)d_in[23];
  const float* x5_w    = (const float*)d_in[24];
  const float* x5_b    = (const float*)d_in[25];
  const float* pl_w    = (const float*)d_in[26];
  const float* pl_b    = (const float*)d_in[27];
  float* out = (float*)d_out;

  // workspace layout (bf16): h (67,108,864) | d3 | x3o | d5 | x5o (16,777,216 each)
  bf16* h   = (bf16*)d_ws;
  bf16* d3  = h + 67108864L;
  bf16* x3o = d3 + 16777216L;
  bf16* d5  = x3o + 16777216L;
  bf16* x5o = d5 + 16777216L;
  // scratch ping-pong lives in d_out (fully overwritten by final_kernel)
  bf16* S0 = (bf16*)d_out;
  bf16* S1 = S0 + 16777216L;

  const long img256 = 256L * 16384;
  const long img64  = 64L * 16384;
  const bf16* a1 = h;                  // channels 0..63
  const bf16* a2 = h + 64L * 16384;    // channels 64..127
  dim3 blk(256);

  ln_pf_kernel<<<4096, blk, 0, stream>>>(x, ln_w, ln_b, pf_w, pf_b, h);

  // branch 1 (a1): l3 chain -> d3 ; x3 chain -> x3o
  dwconv_kernel<1,3,1,0,1><<<65536, blk, 0, stream>>>(a1, img256, lka3_w1, lka3_b1, S0, img64);
  dwconv_kernel<3,1,1,1,0><<<65536, blk, 0, stream>>>(S0, img64,  lka3_w2, lka3_b2, S1, img64);
  dwconv_kernel<5,5,2,4,4><<<65536, blk, 0, stream>>>(S1, img64,  lka3_w3, lka3_b3, d3, img64);
  dwconv_kernel<1,3,1,0,1><<<65536, blk, 0, stream>>>(a1, img256, x3a_w, x3a_b, S0, img64);
  dwconv_kernel<3,1,1,1,0><<<65536, blk, 0, stream>>>(S0, img64,  x3b_w, x3b_b, x3o, img64);

  // branch 2 (a2): l5 chain -> d5 ; x5 -> x5o
  dwconv_kernel<5,5,1,2,2><<<65536, blk, 0, stream>>>(a2, img256, lka5_w1, lka5_b1, S0, img64);
  dwconv_kernel<7,7,2,6,6><<<65536, blk, 0, stream>>>(S0, img64,  lka5_w2, lka5_b2, d5, img64);
  dwconv_kernel<5,5,1,2,2><<<65536, blk, 0, stream>>>(a2, img256, x5_w, x5_b, x5o, img64);

  final_kernel<<<4096, blk, 0, stream>>>(h, d3, x3o, d5, x5o,
                                         lka3_w4, lka3_b4, lka5_w3, lka5_b3,
                                         pl_w, pl_b, scale, x, out);
}

// Round 2
// 1171.388 us; speedup vs baseline: 1.8212x; 1.8212x over previous
//
#include <hip/hip_runtime.h>
#include <hip/hip_bf16.h>

typedef __hip_bfloat16 bf16;

// Geometry: B=16, C=128, H=W=128, HW=16384, S1=S2=64
// h buffer (bf16) layout: (B, 256, HW); ch 0..63 = a1, 64..127 = a2, 128..255 = xh

// ---------------------------------------------------------------------------
// K1: fused LayerNorm (over C) + pointwise 128->256 GEMM, output bf16.
// ---------------------------------------------------------------------------
__global__ __launch_bounds__(256) void ln_pf_kernel(
    const float* __restrict__ x, const float* __restrict__ ln_w,
    const float* __restrict__ ln_b, const float* __restrict__ pf_w,
    const float* __restrict__ pf_b, bf16* __restrict__ h)
{
  __shared__ float xs[128 * 64];
  __shared__ float meanv[64];
  __shared__ float rstdv[64];
  const int tid = threadIdx.x;
  const int g0 = blockIdx.x * 64;
  const int b = g0 >> 14;
  const int hw0 = g0 & 16383;
  const float* xb = x + (long)b * (128L * 16384) + hw0;

  #pragma unroll
  for (int i = 0; i < 32; ++i) {
    int idx = i * 256 + tid;
    int c = idx >> 6, p = idx & 63;
    xs[idx] = xb[(long)c * 16384 + p];
  }
  __syncthreads();

  if (tid < 64) {
    float s = 0.f, ss = 0.f;
    #pragma unroll 8
    for (int c = 0; c < 128; ++c) {
      float v = xs[c * 64 + tid];
      s += v; ss += v * v;
    }
    float m = s * 0.0078125f;
    float var = ss * 0.0078125f - m * m;
    meanv[tid] = m;
    rstdv[tid] = rsqrtf(var + 1e-6f);
  }
  __syncthreads();

  for (int i = 0; i < 32; ++i) {
    int idx = i * 256 + tid;
    int c = idx >> 6, p = idx & 63;
    float v = (xs[idx] - meanv[p]) * rstdv[p];
    xs[idx] = v * ln_w[c] + ln_b[c];
  }
  __syncthreads();

  const int p = tid & 63;
  const int wv = __builtin_amdgcn_readfirstlane(tid >> 6);
  const int ocBase = wv * 64;
  bf16* hp = h + ((long)b * 256) * 16384 + hw0 + p;

  for (int ocb = 0; ocb < 64; ocb += 16) {
    float acc[16];
    const float* wbase = pf_w + (long)(ocBase + ocb) * 128;
    #pragma unroll
    for (int j = 0; j < 16; ++j) acc[j] = pf_b[ocBase + ocb + j];
    #pragma unroll 4
    for (int ic = 0; ic < 128; ++ic) {
      float xv = xs[ic * 64 + p];
      #pragma unroll
      for (int j = 0; j < 16; ++j) acc[j] += wbase[j * 128 + ic] * xv;
    }
    #pragma unroll
    for (int j = 0; j < 16; ++j)
      hp[(long)(ocBase + ocb + j) * 16384] = __float2bfloat16(acc[j]);
  }
}

// ---------------------------------------------------------------------------
// Fused branch-1 depthwise chain. One block = (b, c, 8-row band).
//   t1 = conv1x3(a1)+b1 ; t2 = conv3x1(t1)+b2 ; d3 = conv5x5dil2(t2)+b3
//   u1 = conv1x3(a1)+ba ; x3o = conv3x1(u1)+bb
// Intermediates live in LDS; out-of-valid positions forced to zero so the
// next stage's zero padding semantics hold (bias must not leak into pads).
// ---------------------------------------------------------------------------
__global__ __launch_bounds__(256) void dw_branch1_kernel(
    const bf16* __restrict__ hbuf,
    const float* __restrict__ w1, const float* __restrict__ b1,
    const float* __restrict__ w2, const float* __restrict__ b2,
    const float* __restrict__ w3, const float* __restrict__ b3,
    const float* __restrict__ wa, const float* __restrict__ ba,
    const float* __restrict__ wb, const float* __restrict__ bb,
    bf16* __restrict__ d3, bf16* __restrict__ x3o)
{
  __shared__ float sa[18 * 138];   // a1 band rows y0-5..y0+12, hpad 5
  __shared__ float st1[18 * 136];  // t1, x positions -4..131
  __shared__ float st2[16 * 136];  // t2 rows y0-4..y0+11, x -4..131
  __shared__ float su1[10 * 128];  // u1 rows y0-1..y0+8

  const int t = blockIdx.x;
  const int band = t & 15, c = (t >> 4) & 63, b = t >> 10;
  const int y0 = band * 8;
  const int tid = threadIdx.x;
  const int col = tid & 127, rhalf = tid >> 7;
  const bf16* ap = hbuf + ((long)b * 256 + c) * 16384;

  float W1[3], W2[3], WA[3], WB[3], W3[25];
  #pragma unroll
  for (int k = 0; k < 3; ++k) {
    W1[k] = w1[c * 3 + k]; W2[k] = w2[c * 3 + k];
    WA[k] = wa[c * 3 + k]; WB[k] = wb[c * 3 + k];
  }
  #pragma unroll
  for (int k = 0; k < 25; ++k) W3[k] = w3[c * 25 + k];
  const float B1 = b1[c], B2 = b2[c], B3 = b3[c], BA = ba[c], BB = bb[c];

  // zero horizontal pads of sa
  for (int i = tid; i < 18 * 5; i += 256) {
    int r = i / 5, q = i % 5;
    sa[r * 138 + q] = 0.f;
    sa[r * 138 + 133 + q] = 0.f;
  }
  // load a1 band (zeros outside image)
  #pragma unroll
  for (int rr = rhalf; rr < 18; rr += 2) {
    int gy = y0 - 5 + rr;
    float v = 0.f;
    if ((unsigned)gy < 128u) v = __bfloat162float(ap[gy * 128 + col]);
    sa[rr * 138 + 5 + col] = v;
  }
  __syncthreads();

  // t1 (1x3 horizontal) over all 18 rows, x in -4..131
  #pragma unroll
  for (int rr = rhalf; rr < 18; rr += 2) {
    int gy = y0 - 5 + rr;
    bool rowok = (unsigned)gy < 128u;
    const float* sr = &sa[rr * 138];
    {
      int xq = col - 4;
      float v = W1[0] * sr[col] + W1[1] * sr[col + 1] + W1[2] * sr[col + 2] + B1;
      st1[rr * 136 + col] = (rowok && (unsigned)xq < 128u) ? v : 0.f;
    }
    if (col < 8) {
      int cc = col + 128, xq = cc - 4;
      float v = W1[0] * sr[cc] + W1[1] * sr[cc + 1] + W1[2] * sr[cc + 2] + B1;
      st1[rr * 136 + cc] = (rowok && (unsigned)xq < 128u) ? v : 0.f;
    }
  }
  // u1 (1x3 with x3a) rows y0-1..y0+8, x in 0..127
  #pragma unroll
  for (int r = rhalf; r < 10; r += 2) {
    int gy = y0 - 1 + r;
    const float* sr = &sa[(r + 4) * 138];
    float v = WA[0] * sr[col + 4] + WA[1] * sr[col + 5] + WA[2] * sr[col + 6] + BA;
    su1[r * 128 + col] = ((unsigned)gy < 128u) ? v : 0.f;
  }
  __syncthreads();

  // t2 (3x1 vertical) rows y0-4..y0+11, x in -4..131
  #pragma unroll
  for (int r = rhalf; r < 16; r += 2) {
    int gy = y0 - 4 + r;
    bool rowok = (unsigned)gy < 128u;
    {
      int xq = col - 4;
      float v = W2[0] * st1[r * 136 + col] + W2[1] * st1[(r + 1) * 136 + col] +
                W2[2] * st1[(r + 2) * 136 + col] + B2;
      st2[r * 136 + col] = (rowok && (unsigned)xq < 128u) ? v : 0.f;
    }
    if (col < 8) {
      int cc = col + 128, xq = cc - 4;
      float v = W2[0] * st1[r * 136 + cc] + W2[1] * st1[(r + 1) * 136 + cc] +
                W2[2] * st1[(r + 2) * 136 + cc] + B2;
      st2[r * 136 + cc] = (rowok && (unsigned)xq < 128u) ? v : 0.f;
    }
  }
  __syncthreads();

  // d3 (5x5 dil2 on t2) and x3o (3x1 on u1), rows y0..y0+7
  bf16* d3p = d3 + ((long)b * 64 + c) * 16384;
  bf16* x3p = x3o + ((long)b * 64 + c) * 16384;
  #pragma unroll
  for (int ro = rhalf; ro < 8; ro += 2) {
    float acc = B3;
    #pragma unroll
    for (int u = 0; u < 5; ++u)
      #pragma unroll
      for (int v = 0; v < 5; ++v)
        acc += W3[u * 5 + v] * st2[(ro + 2 * u) * 136 + col + 2 * v];
    d3p[(y0 + ro) * 128 + col] = __float2bfloat16(acc);

    float xo = WB[0] * su1[ro * 128 + col] + WB[1] * su1[(ro + 1) * 128 + col] +
               WB[2] * su1[(ro + 2) * 128 + col] + BB;
    x3p[(y0 + ro) * 128 + col] = __float2bfloat16(xo);
  }
}

// ---------------------------------------------------------------------------
// Fused branch-2 depthwise chain. One block = (b, c, 8-row band).
//   v1 = conv5x5(a2)+b1 ; d5 = conv7x7dil2(v1)+b2 ; x5o = conv5x5(a2)+b5
// ---------------------------------------------------------------------------
__global__ __launch_bounds__(256) void dw_branch2_kernel(
    const bf16* __restrict__ hbuf,
    const float* __restrict__ w1, const float* __restrict__ b1,
    const float* __restrict__ w2, const float* __restrict__ b2,
    const float* __restrict__ w5, const float* __restrict__ b5,
    bf16* __restrict__ d5, bf16* __restrict__ x5o)
{
  __shared__ float sa[24 * 144];  // a2 rows y0-8..y0+15, hpad 8
  __shared__ float sv[20 * 140];  // v1 rows y0-6..y0+13, x -6..133

  const int t = blockIdx.x;
  const int band = t & 15, c = (t >> 4) & 63, b = t >> 10;
  const int y0 = band * 8;
  const int tid = threadIdx.x;
  const int col = tid & 127, rhalf = tid >> 7;
  const bf16* ap = hbuf + ((long)b * 256 + 64 + c) * 16384;

  // zero horizontal pads
  for (int i = tid; i < 24 * 8; i += 256) {
    int r = i >> 3, q = i & 7;
    sa[r * 144 + q] = 0.f;
    sa[r * 144 + 136 + q] = 0.f;
  }
  #pragma unroll
  for (int rr = rhalf; rr < 24; rr += 2) {
    int gy = y0 - 8 + rr;
    float v = 0.f;
    if ((unsigned)gy < 128u) v = __bfloat162float(ap[gy * 128 + col]);
    sa[rr * 144 + 8 + col] = v;
  }
  __syncthreads();

  // v1 = 5x5 pad2 conv; rows y0-6..y0+13, x in -6..133
  {
    float W1[25];
    #pragma unroll
    for (int k = 0; k < 25; ++k) W1[k] = w1[c * 25 + k];
    const float B1 = b1[c];
    #pragma unroll
    for (int r = rhalf; r < 20; r += 2) {
      int gy = y0 - 6 + r;
      bool rowok = (unsigned)gy < 128u;
      {
        int xq = col - 6;
        float v = B1;
        #pragma unroll
        for (int u = 0; u < 5; ++u)
          #pragma unroll
          for (int v5 = 0; v5 < 5; ++v5)
            v += W1[u * 5 + v5] * sa[(r + u) * 144 + col + v5];
        sv[r * 140 + col] = (rowok && (unsigned)xq < 128u) ? v : 0.f;
      }
      if (col < 12) {
        int cc = col + 128, xq = cc - 6;
        float v = B1;
        #pragma unroll
        for (int u = 0; u < 5; ++u)
          #pragma unroll
          for (int v5 = 0; v5 < 5; ++v5)
            v += W1[u * 5 + v5] * sa[(r + u) * 144 + cc + v5];
        sv[r * 140 + cc] = (rowok && (unsigned)xq < 128u) ? v : 0.f;
      }
    }
  }
  // x5o = 5x5 pad2 conv directly on a2, rows y0..y0+7
  {
    float W5[25];
    #pragma unroll
    for (int k = 0; k < 25; ++k) W5[k] = w5[c * 25 + k];
    const float B5 = b5[c];
    bf16* x5p = x5o + ((long)b * 64 + c) * 16384;
    #pragma unroll
    for (int ro = rhalf; ro < 8; ro += 2) {
      float acc = B5;
      #pragma unroll
      for (int u = 0; u < 5; ++u)
        #pragma unroll
        for (int v5 = 0; v5 < 5; ++v5)
          acc += W5[u * 5 + v5] * sa[(ro + 6 + u) * 144 + col + 6 + v5];
      x5p[(y0 + ro) * 128 + col] = __float2bfloat16(acc);
    }
  }
  __syncthreads();

  // d5 = 7x7 dil2 conv on v1, rows y0..y0+7
  {
    float W2[49];
    #pragma unroll
    for (int k = 0; k < 49; ++k) W2[k] = w2[c * 49 + k];
    const float B2 = b2[c];
    bf16* d5p = d5 + ((long)b * 64 + c) * 16384;
    #pragma unroll
    for (int ro = rhalf; ro < 8; ro += 2) {
      float acc = B2;
      #pragma unroll
      for (int u = 0; u < 7; ++u)
        #pragma unroll
        for (int v7 = 0; v7 < 7; ++v7)
          acc += W2[u * 7 + v7] * sv[(ro + 2 * u) * 140 + col + 2 * v7];
      d5p[(y0 + ro) * 128 + col] = __float2bfloat16(acc);
    }
  }
}

// ---------------------------------------------------------------------------
// K4: fused finale (unchanged from round 0).
// ---------------------------------------------------------------------------
__global__ __launch_bounds__(256) void final_kernel(
    const bf16* __restrict__ h, const bf16* __restrict__ d3,
    const bf16* __restrict__ x3o, const bf16* __restrict__ d5,
    const bf16* __restrict__ x5o, const float* __restrict__ w4,
    const float* __restrict__ b4, const float* __restrict__ w5,
    const float* __restrict__ b5, const float* __restrict__ plw,
    const float* __restrict__ plb, const float* __restrict__ scale,
    const float* __restrict__ x, float* __restrict__ out)
{
  __shared__ float sm[128 * 64];
  const int tid = threadIdx.x;
  const int p = tid & 63;
  const int wv = __builtin_amdgcn_readfirstlane(tid >> 6);
  const int g0 = blockIdx.x * 64;
  const int b = g0 >> 14;
  const int hw0 = g0 & 16383;
  const long base64 = (long)b * (64L * 16384) + hw0;

  #pragma unroll
  for (int i = 0; i < 16; ++i) {
    int idx = i * 256 + tid;
    int c = idx >> 6, q = idx & 63;
    sm[idx]        = __bfloat162float(d3[base64 + (long)c * 16384 + q]);
    sm[4096 + idx] = __bfloat162float(d5[base64 + (long)c * 16384 + q]);
  }
  __syncthreads();

  float gv[32];
  #pragma unroll
  for (int j = 0; j < 16; ++j) {
    int oc = wv * 16 + j;
    float acc1 = b4[oc], acc2 = b5[oc];
    #pragma unroll 4
    for (int ic = 0; ic < 64; ++ic) {
      acc1 += w4[oc * 64 + ic] * sm[ic * 64 + p];
      acc2 += w5[oc * 64 + ic] * sm[4096 + ic * 64 + p];
    }
    float attn1 = acc1 * __bfloat162float(x3o[base64 + (long)oc * 16384 + p]);
    float attn2 = acc2 * __bfloat162float(x5o[base64 + (long)oc * 16384 + p]);
    float xh1 = __bfloat162float(h[((long)b * 256 + 128 + oc) * 16384 + hw0 + p]);
    float xh2 = __bfloat162float(h[((long)b * 256 + 192 + oc) * 16384 + hw0 + p]);
    gv[j]      = xh1 * attn1;
    gv[16 + j] = xh2 * attn2;
  }
  __syncthreads();
  #pragma unroll
  for (int j = 0; j < 16; ++j) {
    sm[(wv * 16 + j) * 64 + p]       = gv[j];
    sm[(64 + wv * 16 + j) * 64 + p]  = gv[16 + j];
  }
  __syncthreads();

  const int ocB = wv * 32;
  for (int ocb = 0; ocb < 32; ocb += 16) {
    float acc[16];
    const float* wbase = plw + (long)(ocB + ocb) * 128;
    #pragma unroll
    for (int j = 0; j < 16; ++j) acc[j] = plb[ocB + ocb + j];
    #pragma unroll 4
    for (int ic = 0; ic < 128; ++ic) {
      float gvv = sm[ic * 64 + p];
      #pragma unroll
      for (int j = 0; j < 16; ++j) acc[j] += wbase[j * 128 + ic] * gvv;
    }
    #pragma unroll
    for (int j = 0; j < 16; ++j) {
      int oc = ocB + ocb + j;
      long xi = ((long)b * 128 + oc) * 16384 + hw0 + p;
      out[xi] = acc[j] * scale[oc] + x[xi];
    }
  }
}

// ---------------------------------------------------------------------------
extern "C" void kernel_launch(void* const* d_in, const int* in_sizes, int n_in,
                              void* d_out, int out_size, void* d_ws, size_t ws_size,
                              hipStream_t stream)
{
  (void)in_sizes; (void)n_in; (void)out_size; (void)ws_size;
  const float* x       = (const float*)d_in[0];
  const float* ln_w    = (const float*)d_in[1];
  const float* ln_b    = (const float*)d_in[2];
  const float* scale   = (const float*)d_in[3];
  const float* pf_w    = (const float*)d_in[4];
  const float* pf_b    = (const float*)d_in[5];
  const float* lka3_w1 = (const float*)d_in[6];
  const float* lka3_b1 = (const float*)d_in[7];
  const float* lka3_w2 = (const float*)d_in[8];
  const float* lka3_b2 = (const float*)d_in[9];
  const float* lka3_w3 = (const float*)d_in[10];
  const float* lka3_b3 = (const float*)d_in[11];
  const float* lka3_w4 = (const float*)d_in[12];
  const float* lka3_b4 = (const float*)d_in[13];
  const float* lka5_w1 = (const float*)d_in[14];
  const float* lka5_b1 = (const float*)d_in[15];
  const float* lka5_w2 = (const float*)d_in[16];
  const float* lka5_b2 = (const float*)d_in[17];
  const float* lka5_w3 = (const float*)d_in[18];
  const float* lka5_b3 = (const float*)d_in[19];
  const float* x3a_w   = (const float*)d_in[20];
  const float* x3a_b   = (const float*)d_in[21];
  const float* x3b_w   = (const float*)d_in[22];
  const float* x3b_b   = (const float*)d_in[23];
  const float* x5_w    = (const float*)d_in[24];
  const float* x5_b    = (const float*)d_in[25];
  const float* pl_w    = (const float*)d_in[26];
  const float* pl_b    = (const float*)d_in[27];
  float* out = (float*)d_out;

  // workspace layout (bf16): h (67,108,864) | d3 | x3o | d5 | x5o
  bf16* h   = (bf16*)d_ws;
  bf16* d3  = h + 67108864L;
  bf16* x3o = d3 + 16777216L;
  bf16* d5  = x3o + 16777216L;
  bf16* x5o = d5 + 16777216L;

  dim3 blk(256);

  ln_pf_kernel<<<4096, blk, 0, stream>>>(x, ln_w, ln_b, pf_w, pf_b, h);

  dw_branch1_kernel<<<16384, blk, 0, stream>>>(
      h, lka3_w1, lka3_b1, lka3_w2, lka3_b2, lka3_w3, lka3_b3,
      x3a_w, x3a_b, x3b_w, x3b_b, d3, x3o);

  dw_branch2_kernel<<<16384, blk, 0, stream>>>(
      h, lka5_w1, lka5_b1, lka5_w2, lka5_b2, x5_w, x5_b, d5, x5o);

  final_kernel<<<4096, blk, 0, stream>>>(h, d3, x3o, d5, x5o,
                                         lka3_w4, lka3_b4, lka5_w3, lka5_b3,
                                         pl_w, pl_b, scale, x, out);
}

// Round 3
// 677.900 us; speedup vs baseline: 3.1470x; 1.7280x over previous
//
#include <hip/hip_runtime.h>
#include <hip/hip_bf16.h>

typedef __hip_bfloat16 bf16;
typedef unsigned short ushort_t;
typedef float f32x4 __attribute__((ext_vector_type(4)));
typedef short bf16x8 __attribute__((ext_vector_type(8)));

#define MFMA16(a, b, c) __builtin_amdgcn_mfma_f32_16x16x32_bf16(a, b, c, 0, 0, 0)

__device__ inline ushort_t f2b(float f) {
  bf16 h = __float2bfloat16(f);
  return __builtin_bit_cast(ushort_t, h);
}
__device__ inline float b2f(ushort_t u) {
  bf16 h = __builtin_bit_cast(bf16, u);
  return __bfloat162float(h);
}

// Geometry: B=16, C=128, H=W=128, HW=16384, S1=S2=64
// h buffer (bf16) layout: (B, 256, HW); ch 0..63 = a1, 64..127 = a2, 128..255 = xh
// MFMA frag layouts (16x16x32 bf16, m89/m91-verified):
//   A: lane l holds A[m = l&15][k = (l>>4)*8 + j], j=0..7
//   B: lane l holds W[n = l&15][k = (l>>4)*8 + j]  (B^T-input convention)
//   D: lane l reg r holds D[m = (l>>4)*4 + r][n = l&15]

// ---------------------------------------------------------------------------
// Weight pre-pack kernels (bf16, B-fragment order).
// ---------------------------------------------------------------------------
__global__ __launch_bounds__(256) void prepack_pf(
    const float* __restrict__ pf_w, ushort_t* __restrict__ pf_wp)
{
  int idx = blockIdx.x * 256 + threadIdx.x;  // 32768 = 16 tiles * 4 kc * 64 * 8
  int j = idx & 7, lane = (idx >> 3) & 63, kc = (idx >> 9) & 3, t = idx >> 11;
  int oc = t * 16 + (lane & 15), ic = kc * 32 + (lane >> 4) * 8 + j;
  pf_wp[idx] = f2b(pf_w[oc * 128 + ic]);
}

__global__ __launch_bounds__(256) void prepack_small(
    const float* __restrict__ w4, const float* __restrict__ w5,
    const float* __restrict__ plw, ushort_t* __restrict__ dst)
{
  int idx = blockIdx.x * 256 + threadIdx.x;  // 24576: [0,4096) w4p, [4096,8192) w5p, rest plwp
  if (idx < 8192) {
    const float* src = (idx < 4096) ? w4 : w5;
    int k = idx & 4095;
    int j = k & 7, lane = (k >> 3) & 63, kc = (k >> 9) & 1, t = k >> 10;
    int oc = t * 16 + (lane & 15), ic = kc * 32 + (lane >> 4) * 8 + j;
    dst[idx] = f2b(src[oc * 64 + ic]);
  } else {
    int k = idx - 8192;  // 16384 = 8 tiles * 4 kc * 64 * 8
    int j = k & 7, lane = (k >> 3) & 63, kc = (k >> 9) & 3, t = k >> 11;
    int oc = t * 16 + (lane & 15), ic = kc * 32 + (lane >> 4) * 8 + j;
    dst[idx] = f2b(plw[oc * 128 + ic]);
  }
}

// ---------------------------------------------------------------------------
// K1: fused LayerNorm + pointwise 128->256 via bf16 MFMA. Block = 64 px.
// ---------------------------------------------------------------------------
__global__ __launch_bounds__(256) void ln_pf_mfma(
    const float* __restrict__ x, const float* __restrict__ ln_w,
    const float* __restrict__ ln_b, const ushort_t* __restrict__ pf_wp,
    const float* __restrict__ pf_b, ushort_t* __restrict__ h)
{
  __shared__ __attribute__((aligned(16))) unsigned char sm[34816];
  ushort_t* xs = (ushort_t*)sm;             // [64 px][136] bf16 (A-layout, pad 8)
  float* red = (float*)(sm + 17408);        // partial sums [2][4][64]
  float* mrs = (float*)(sm + 17408 + 2048); // mean[64], rstd[64]

  const int tid = threadIdx.x;
  const int p = tid & 63, cg = tid >> 6;
  const int g0 = blockIdx.x * 64;
  const int b = g0 >> 14, hw0 = g0 & 16383;
  const float* xp = x + (long)b * (128L * 16384) + hw0 + p;

  float v[32];
  #pragma unroll
  for (int i = 0; i < 32; ++i) v[i] = xp[(long)(cg * 32 + i) * 16384];
  float s = 0.f, ss = 0.f;
  #pragma unroll
  for (int i = 0; i < 32; ++i) { s += v[i]; ss += v[i] * v[i]; }
  red[cg * 64 + p] = s;
  red[256 + cg * 64 + p] = ss;
  __syncthreads();
  if (tid < 64) {
    float st = red[tid] + red[64 + tid] + red[128 + tid] + red[192 + tid];
    float sst = red[256 + tid] + red[320 + tid] + red[384 + tid] + red[448 + tid];
    float m = st * 0.0078125f;
    float var = sst * 0.0078125f - m * m;
    mrs[tid] = m;
    mrs[64 + tid] = rsqrtf(var + 1e-6f);
  }
  __syncthreads();
  {
    float m = mrs[p], rs = mrs[64 + p];
    #pragma unroll
    for (int i = 0; i < 32; ++i) {
      int c = cg * 32 + i;
      xs[p * 136 + c] = f2b((v[i] - m) * rs * ln_w[c] + ln_b[c]);
    }
  }
  __syncthreads();

  const int l = tid & 63, lm = l & 15, q = l >> 4;
  const int wv = __builtin_amdgcn_readfirstlane(tid >> 6);
  f32x4 acc[4][4];
  #pragma unroll
  for (int a = 0; a < 4; ++a)
    #pragma unroll
    for (int n = 0; n < 4; ++n) acc[a][n] = {0.f, 0.f, 0.f, 0.f};

  #pragma unroll
  for (int kc = 0; kc < 4; ++kc) {
    bf16x8 af[4], bfr[4];
    #pragma unroll
    for (int mt = 0; mt < 4; ++mt)
      af[mt] = *(const bf16x8*)&xs[(mt * 16 + lm) * 136 + kc * 32 + q * 8];
    #pragma unroll
    for (int nt = 0; nt < 4; ++nt)
      bfr[nt] = *(const bf16x8*)&pf_wp[(((wv * 4 + nt) * 4 + kc) * 64 + l) * 8];
    #pragma unroll
    for (int mt = 0; mt < 4; ++mt)
      #pragma unroll
      for (int nt = 0; nt < 4; ++nt)
        acc[mt][nt] = MFMA16(af[mt], bfr[nt], acc[mt][nt]);
  }
  __syncthreads();

  // epilogue: + bias, transpose via LDS to [oc][px], then coalesced store
  ushort_t* hst = (ushort_t*)sm;  // [256 oc][68 px] bf16
  #pragma unroll
  for (int nt = 0; nt < 4; ++nt) {
    int oc = wv * 64 + nt * 16 + lm;
    float bias = pf_b[oc];
    #pragma unroll
    for (int mt = 0; mt < 4; ++mt) {
      int px0 = mt * 16 + q * 4;
      union { ushort_t u[4]; uint2 w; } pk;
      #pragma unroll
      for (int r = 0; r < 4; ++r) pk.u[r] = f2b(acc[mt][nt][r] + bias);
      *(uint2*)&hst[oc * 68 + px0] = pk.w;
    }
  }
  __syncthreads();
  {
    int px = (tid & 31) * 2;
    int ocb = tid >> 5;
    ushort_t* hp = h + (long)b * 256 * 16384 + hw0 + px;
    #pragma unroll
    for (int i = 0; i < 32; ++i) {
      int oc = ocb + 8 * i;
      *(unsigned*)(hp + (long)oc * 16384) = *(unsigned*)&hst[oc * 68 + px];
    }
  }
}

// ---------------------------------------------------------------------------
// Fused branch-1 depthwise chain (unchanged from round 2).
// ---------------------------------------------------------------------------
__global__ __launch_bounds__(256) void dw_branch1_kernel(
    const bf16* __restrict__ hbuf,
    const float* __restrict__ w1, const float* __restrict__ b1,
    const float* __restrict__ w2, const float* __restrict__ b2,
    const float* __restrict__ w3, const float* __restrict__ b3,
    const float* __restrict__ wa, const float* __restrict__ ba,
    const float* __restrict__ wb, const float* __restrict__ bb,
    bf16* __restrict__ d3, bf16* __restrict__ x3o)
{
  __shared__ float sa[18 * 138];
  __shared__ float st1[18 * 136];
  __shared__ float st2[16 * 136];
  __shared__ float su1[10 * 128];

  const int t = blockIdx.x;
  const int band = t & 15, c = (t >> 4) & 63, b = t >> 10;
  const int y0 = band * 8;
  const int tid = threadIdx.x;
  const int col = tid & 127, rhalf = tid >> 7;
  const bf16* ap = hbuf + ((long)b * 256 + c) * 16384;

  float W1[3], W2[3], WA[3], WB[3], W3[25];
  #pragma unroll
  for (int k = 0; k < 3; ++k) {
    W1[k] = w1[c * 3 + k]; W2[k] = w2[c * 3 + k];
    WA[k] = wa[c * 3 + k]; WB[k] = wb[c * 3 + k];
  }
  #pragma unroll
  for (int k = 0; k < 25; ++k) W3[k] = w3[c * 25 + k];
  const float B1 = b1[c], B2 = b2[c], B3 = b3[c], BA = ba[c], BB = bb[c];

  for (int i = tid; i < 18 * 5; i += 256) {
    int r = i / 5, qq = i % 5;
    sa[r * 138 + qq] = 0.f;
    sa[r * 138 + 133 + qq] = 0.f;
  }
  #pragma unroll
  for (int rr = rhalf; rr < 18; rr += 2) {
    int gy = y0 - 5 + rr;
    float v = 0.f;
    if ((unsigned)gy < 128u) v = __bfloat162float(ap[gy * 128 + col]);
    sa[rr * 138 + 5 + col] = v;
  }
  __syncthreads();

  #pragma unroll
  for (int rr = rhalf; rr < 18; rr += 2) {
    int gy = y0 - 5 + rr;
    bool rowok = (unsigned)gy < 128u;
    const float* sr = &sa[rr * 138];
    {
      int xq = col - 4;
      float v = W1[0] * sr[col] + W1[1] * sr[col + 1] + W1[2] * sr[col + 2] + B1;
      st1[rr * 136 + col] = (rowok && (unsigned)xq < 128u) ? v : 0.f;
    }
    if (col < 8) {
      int cc = col + 128, xq = cc - 4;
      float v = W1[0] * sr[cc] + W1[1] * sr[cc + 1] + W1[2] * sr[cc + 2] + B1;
      st1[rr * 136 + cc] = (rowok && (unsigned)xq < 128u) ? v : 0.f;
    }
  }
  #pragma unroll
  for (int r = rhalf; r < 10; r += 2) {
    int gy = y0 - 1 + r;
    const float* sr = &sa[(r + 4) * 138];
    float v = WA[0] * sr[col + 4] + WA[1] * sr[col + 5] + WA[2] * sr[col + 6] + BA;
    su1[r * 128 + col] = ((unsigned)gy < 128u) ? v : 0.f;
  }
  __syncthreads();

  #pragma unroll
  for (int r = rhalf; r < 16; r += 2) {
    int gy = y0 - 4 + r;
    bool rowok = (unsigned)gy < 128u;
    {
      int xq = col - 4;
      float v = W2[0] * st1[r * 136 + col] + W2[1] * st1[(r + 1) * 136 + col] +
                W2[2] * st1[(r + 2) * 136 + col] + B2;
      st2[r * 136 + col] = (rowok && (unsigned)xq < 128u) ? v : 0.f;
    }
    if (col < 8) {
      int cc = col + 128, xq = cc - 4;
      float v = W2[0] * st1[r * 136 + cc] + W2[1] * st1[(r + 1) * 136 + cc] +
                W2[2] * st1[(r + 2) * 136 + cc] + B2;
      st2[r * 136 + cc] = (rowok && (unsigned)xq < 128u) ? v : 0.f;
    }
  }
  __syncthreads();

  bf16* d3p = d3 + ((long)b * 64 + c) * 16384;
  bf16* x3p = x3o + ((long)b * 64 + c) * 16384;
  #pragma unroll
  for (int ro = rhalf; ro < 8; ro += 2) {
    float acc = B3;
    #pragma unroll
    for (int u = 0; u < 5; ++u)
      #pragma unroll
      for (int v = 0; v < 5; ++v)
        acc += W3[u * 5 + v] * st2[(ro + 2 * u) * 136 + col + 2 * v];
    d3p[(y0 + ro) * 128 + col] = __float2bfloat16(acc);

    float xo = WB[0] * su1[ro * 128 + col] + WB[1] * su1[(ro + 1) * 128 + col] +
               WB[2] * su1[(ro + 2) * 128 + col] + BB;
    x3p[(y0 + ro) * 128 + col] = __float2bfloat16(xo);
  }
}

// ---------------------------------------------------------------------------
// Fused branch-2 depthwise chain (unchanged from round 2).
// ---------------------------------------------------------------------------
__global__ __launch_bounds__(256) void dw_branch2_kernel(
    const bf16* __restrict__ hbuf,
    const float* __restrict__ w1, const float* __restrict__ b1,
    const float* __restrict__ w2, const float* __restrict__ b2,
    const float* __restrict__ w5, const float* __restrict__ b5,
    bf16* __restrict__ d5, bf16* __restrict__ x5o)
{
  __shared__ float sa[24 * 144];
  __shared__ float sv[20 * 140];

  const int t = blockIdx.x;
  const int band = t & 15, c = (t >> 4) & 63, b = t >> 10;
  const int y0 = band * 8;
  const int tid = threadIdx.x;
  const int col = tid & 127, rhalf = tid >> 7;
  const bf16* ap = hbuf + ((long)b * 256 + 64 + c) * 16384;

  for (int i = tid; i < 24 * 8; i += 256) {
    int r = i >> 3, qq = i & 7;
    sa[r * 144 + qq] = 0.f;
    sa[r * 144 + 136 + qq] = 0.f;
  }
  #pragma unroll
  for (int rr = rhalf; rr < 24; rr += 2) {
    int gy = y0 - 8 + rr;
    float v = 0.f;
    if ((unsigned)gy < 128u) v = __bfloat162float(ap[gy * 128 + col]);
    sa[rr * 144 + 8 + col] = v;
  }
  __syncthreads();

  {
    float W1[25];
    #pragma unroll
    for (int k = 0; k < 25; ++k) W1[k] = w1[c * 25 + k];
    const float B1 = b1[c];
    #pragma unroll
    for (int r = rhalf; r < 20; r += 2) {
      int gy = y0 - 6 + r;
      bool rowok = (unsigned)gy < 128u;
      {
        int xq = col - 6;
        float v = B1;
        #pragma unroll
        for (int u = 0; u < 5; ++u)
          #pragma unroll
          for (int v5 = 0; v5 < 5; ++v5)
            v += W1[u * 5 + v5] * sa[(r + u) * 144 + col + v5];
        sv[r * 140 + col] = (rowok && (unsigned)xq < 128u) ? v : 0.f;
      }
      if (col < 12) {
        int cc = col + 128, xq = cc - 6;
        float v = B1;
        #pragma unroll
        for (int u = 0; u < 5; ++u)
          #pragma unroll
          for (int v5 = 0; v5 < 5; ++v5)
            v += W1[u * 5 + v5] * sa[(r + u) * 144 + cc + v5];
        sv[r * 140 + cc] = (rowok && (unsigned)xq < 128u) ? v : 0.f;
      }
    }
  }
  {
    float W5[25];
    #pragma unroll
    for (int k = 0; k < 25; ++k) W5[k] = w5[c * 25 + k];
    const float B5 = b5[c];
    bf16* x5p = x5o + ((long)b * 64 + c) * 16384;
    #pragma unroll
    for (int ro = rhalf; ro < 8; ro += 2) {
      float acc = B5;
      #pragma unroll
      for (int u = 0; u < 5; ++u)
        #pragma unroll
        for (int v5 = 0; v5 < 5; ++v5)
          acc += W5[u * 5 + v5] * sa[(ro + 6 + u) * 144 + col + 6 + v5];
      x5p[(y0 + ro) * 128 + col] = __float2bfloat16(acc);
    }
  }
  __syncthreads();

  {
    float W2[49];
    #pragma unroll
    for (int k = 0; k < 49; ++k) W2[k] = w2[c * 49 + k];
    const float B2 = b2[c];
    bf16* d5p = d5 + ((long)b * 64 + c) * 16384;
    #pragma unroll
    for (int ro = rhalf; ro < 8; ro += 2) {
      float acc = B2;
      #pragma unroll
      for (int u = 0; u < 7; ++u)
        #pragma unroll
        for (int v7 = 0; v7 < 7; ++v7)
          acc += W2[u * 7 + v7] * sv[(ro + 2 * u) * 140 + col + 2 * v7];
      d5p[(y0 + ro) * 128 + col] = __float2bfloat16(acc);
    }
  }
}

// ---------------------------------------------------------------------------
// K4: fused finale via bf16 MFMA. Block = 64 px.
// ---------------------------------------------------------------------------
__global__ __launch_bounds__(256) void final_mfma(
    const ushort_t* __restrict__ h, const ushort_t* __restrict__ d3,
    const ushort_t* __restrict__ x3o, const ushort_t* __restrict__ d5,
    const ushort_t* __restrict__ x5o,
    const ushort_t* __restrict__ w4p, const float* __restrict__ b4,
    const ushort_t* __restrict__ w5p, const float* __restrict__ b5,
    const ushort_t* __restrict__ plwp, const float* __restrict__ plb,
    const float* __restrict__ scale, const float* __restrict__ x,
    float* __restrict__ out)
{
  __shared__ __attribute__((aligned(16))) unsigned char sm[35840];
  ushort_t* A3 = (ushort_t*)sm;             // [64 px][72] bf16
  ushort_t* A5 = (ushort_t*)(sm + 9216);    // [64 px][72] bf16
  ushort_t* gA = (ushort_t*)(sm + 18432);   // [64 px][136] bf16

  const int tid = threadIdx.x;
  const int g0 = blockIdx.x * 64;
  const int b = g0 >> 14, hw0 = g0 & 16383;
  const long base64 = (long)b * 64 * 16384 + hw0;
  const long base256 = (long)b * 256 * 16384 + hw0;
  const int p = tid & 63;

  #pragma unroll
  for (int i = 0; i < 16; ++i) {
    int ch = (tid >> 6) + 4 * i;
    A3[p * 72 + ch] = d3[base64 + (long)ch * 16384 + p];
    A5[p * 72 + ch] = d5[base64 + (long)ch * 16384 + p];
  }
  __syncthreads();

  const int l = tid & 63, lm = l & 15, q = l >> 4;
  const int wv = __builtin_amdgcn_readfirstlane(tid >> 6);

  f32x4 ac1[4], ac2[4];
  #pragma unroll
  for (int n = 0; n < 4; ++n) { ac1[n] = {0.f,0.f,0.f,0.f}; ac2[n] = {0.f,0.f,0.f,0.f}; }
  #pragma unroll
  for (int kc = 0; kc < 2; ++kc) {
    bf16x8 a3f = *(const bf16x8*)&A3[(wv * 16 + lm) * 72 + kc * 32 + q * 8];
    bf16x8 a5f = *(const bf16x8*)&A5[(wv * 16 + lm) * 72 + kc * 32 + q * 8];
    #pragma unroll
    for (int nt = 0; nt < 4; ++nt) {
      bf16x8 bw4 = *(const bf16x8*)&w4p[((nt * 2 + kc) * 64 + l) * 8];
      bf16x8 bw5 = *(const bf16x8*)&w5p[((nt * 2 + kc) * 64 + l) * 8];
      ac1[nt] = MFMA16(a3f, bw4, ac1[nt]);
      ac2[nt] = MFMA16(a5f, bw5, ac2[nt]);
    }
  }

  // gating: attn = (conv + bias) * xNo ; g = xh * attn -> gA in A-layout
  #pragma unroll
  for (int nt = 0; nt < 4; ++nt) {
    int oc = nt * 16 + lm;
    float bb1 = b4[oc], bb2 = b5[oc];
    #pragma unroll
    for (int r = 0; r < 4; ++r) {
      int px = wv * 16 + q * 4 + r;
      float at1 = (ac1[nt][r] + bb1) * b2f(x3o[base64 + (long)oc * 16384 + px]);
      float at2 = (ac2[nt][r] + bb2) * b2f(x5o[base64 + (long)oc * 16384 + px]);
      float g1 = b2f(h[base256 + (long)(128 + oc) * 16384 + px]) * at1;
      float g2 = b2f(h[base256 + (long)(192 + oc) * 16384 + px]) * at2;
      gA[px * 136 + oc]      = f2b(g1);
      gA[px * 136 + 64 + oc] = f2b(g2);
    }
  }
  __syncthreads();

  f32x4 ap[4][2];
  #pragma unroll
  for (int mt = 0; mt < 4; ++mt) { ap[mt][0] = {0.f,0.f,0.f,0.f}; ap[mt][1] = {0.f,0.f,0.f,0.f}; }
  #pragma unroll
  for (int kc = 0; kc < 4; ++kc) {
    bf16x8 af[4];
    #pragma unroll
    for (int mt = 0; mt < 4; ++mt)
      af[mt] = *(const bf16x8*)&gA[(mt * 16 + lm) * 136 + kc * 32 + q * 8];
    #pragma unroll
    for (int j = 0; j < 2; ++j) {
      bf16x8 bp = *(const bf16x8*)&plwp[(((wv * 2 + j) * 4 + kc) * 64 + l) * 8];
      #pragma unroll
      for (int mt = 0; mt < 4; ++mt)
        ap[mt][j] = MFMA16(af[mt], bp, ap[mt][j]);
    }
  }
  __syncthreads();

  float* outL = (float*)sm;  // [128 oc][68 px] fp32
  #pragma unroll
  for (int j = 0; j < 2; ++j) {
    int oc = (wv * 2 + j) * 16 + lm;
    float sc = scale[oc], bb = plb[oc];
    #pragma unroll
    for (int mt = 0; mt < 4; ++mt) {
      int px0 = mt * 16 + q * 4;
      f32x4 vv;
      #pragma unroll
      for (int r = 0; r < 4; ++r) vv[r] = (ap[mt][j][r] + bb) * sc;
      *(f32x4*)&outL[oc * 68 + px0] = vv;
    }
  }
  __syncthreads();
  {
    const float* xp = x + (long)b * 128 * 16384 + hw0 + p;
    float* op = out + (long)b * 128 * 16384 + hw0 + p;
    #pragma unroll
    for (int i = 0; i < 32; ++i) {
      int oc = (tid >> 6) + 4 * i;
      op[(long)oc * 16384] = outL[oc * 68 + p] + xp[(long)oc * 16384];
    }
  }
}

// ---------------------------------------------------------------------------
extern "C" void kernel_launch(void* const* d_in, const int* in_sizes, int n_in,
                              void* d_out, int out_size, void* d_ws, size_t ws_size,
                              hipStream_t stream)
{
  (void)in_sizes; (void)n_in; (void)out_size; (void)ws_size;
  const float* x       = (const float*)d_in[0];
  const float* ln_w    = (const float*)d_in[1];
  const float* ln_b    = (const float*)d_in[2];
  const float* scale   = (const float*)d_in[3];
  const float* pf_w    = (const float*)d_in[4];
  const float* pf_b    = (const float*)d_in[5];
  const float* lka3_w1 = (const float*)d_in[6];
  const float* lka3_b1 = (const float*)d_in[7];
  const float* lka3_w2 = (const float*)d_in[8];
  const float* lka3_b2 = (const float*)d_in[9];
  const float* lka3_w3 = (const float*)d_in[10];
  const float* lka3_b3 = (const float*)d_in[11];
  const float* lka3_w4 = (const float*)d_in[12];
  const float* lka3_b4 = (const float*)d_in[13];
  const float* lka5_w1 = (const float*)d_in[14];
  const float* lka5_b1 = (const float*)d_in[15];
  const float* lka5_w2 = (const float*)d_in[16];
  const float* lka5_b2 = (const float*)d_in[17];
  const float* lka5_w3 = (const float*)d_in[18];
  const float* lka5_b3 = (const float*)d_in[19];
  const float* x3a_w   = (const float*)d_in[20];
  const float* x3a_b   = (const float*)d_in[21];
  const float* x3b_w   = (const float*)d_in[22];
  const float* x3b_b   = (const float*)d_in[23];
  const float* x5_w    = (const float*)d_in[24];
  const float* x5_b    = (const float*)d_in[25];
  const float* pl_w    = (const float*)d_in[26];
  const float* pl_b    = (const float*)d_in[27];
  float* out = (float*)d_out;

  // ws layout (bf16): h (67,108,864 el) | d3 | x3o | d5 | x5o (16,777,216 el each)
  bf16* h   = (bf16*)d_ws;
  bf16* d3  = h + 67108864L;
  bf16* x3o = d3 + 16777216L;
  bf16* d5  = x3o + 16777216L;
  bf16* x5o = d5 + 16777216L;
  // packed weights:
  //  - pf_wp lives in d_out (free until final_mfma overwrites it)
  //  - w4p/w5p/plwp live in the a1 region of h (dead after dw kernels;
  //    packed after the dw launches, before final)
  ushort_t* pf_wp = (ushort_t*)d_out;
  ushort_t* wsmall = (ushort_t*)d_ws;   // w4p @0, w5p @4096, plwp @8192 (elements)

  dim3 blk(256);

  prepack_pf<<<128, blk, 0, stream>>>(pf_w, pf_wp);
  ln_pf_mfma<<<4096, blk, 0, stream>>>(x, ln_w, ln_b, pf_wp, pf_b, (ushort_t*)h);

  dw_branch1_kernel<<<16384, blk, 0, stream>>>(
      h, lka3_w1, lka3_b1, lka3_w2, lka3_b2, lka3_w3, lka3_b3,
      x3a_w, x3a_b, x3b_w, x3b_b, d3, x3o);

  dw_branch2_kernel<<<16384, blk, 0, stream>>>(
      h, lka5_w1, lka5_b1, lka5_w2, lka5_b2, x5_w, x5_b, d5, x5o);

  prepack_small<<<96, blk, 0, stream>>>(lka3_w4, lka5_w3, pl_w, wsmall);

  final_mfma<<<4096, blk, 0, stream>>>(
      (const ushort_t*)h, (const ushort_t*)d3, (const ushort_t*)x3o,
      (const ushort_t*)d5, (const ushort_t*)x5o,
      wsmall, lka3_b4, wsmall + 4096, lka5_b3,
      wsmall + 8192, pl_b, scale, x, out);
}